// Round 1
// baseline (32.154 us; speedup 1.0000x reference)
//
#include <hip/hip_runtime.h>

// Problem constants (match the reference)
#define Bv 32
#define Sv 1024
#define Hv 1024
#define Vv 250002

// ---------------------------------------------------------------------------
// Kernel 1: zero the [B, V] output table (float4-vectorized, grid-stride).
// B*V = 8,000,064 floats = 2,000,016 float4 — divisible by 4, no tail.
// ---------------------------------------------------------------------------
__global__ __launch_bounds__(256) void zero_out_kernel(float4* __restrict__ out, int n4) {
    int i = blockIdx.x * blockDim.x + threadIdx.x;
    int stride = gridDim.x * blockDim.x;
    for (; i < n4; i += stride) {
        out[i] = make_float4(0.f, 0.f, 0.f, 0.f);
    }
}

// ---------------------------------------------------------------------------
// Kernel 2: per-(b,s) dot(hidden[b,s,:], W) + bias, ReLU, scatter-max.
// One 64-lane wave per row; 4 waves (256 threads) per block.
// Each lane reads 4 x float4 = 64 B of the 4 KB row (coalesced).
// W (4 KB) is read by every wave -> L1/L2 resident, negligible HBM.
// Scatter: atomicMax on the int bit pattern — correct because every stored
// value is >= 0 (post-ReLU) and the table is zero-initialized; non-negative
// IEEE-754 floats are order-isomorphic to their signed-int bit patterns.
// Skipping ids < 4 is equivalent to the reference's final set(0.0) on
// columns {0,1,2,3}.
// ---------------------------------------------------------------------------
__global__ __launch_bounds__(256) void dot_scatter_kernel(
        const float* __restrict__ hidden,   // [B*S, H]
        const int*   __restrict__ ids,      // [B*S]
        const float* __restrict__ W,        // [H]
        const float* __restrict__ bias,     // [1]
        float*       __restrict__ out)      // [B, V]
{
    const int wave = threadIdx.x >> 6;           // 0..3
    const int lane = threadIdx.x & 63;
    const int row  = blockIdx.x * 4 + wave;      // (b*S + s) in [0, B*S)
    if (row >= Bv * Sv) return;

    const float4* hp = reinterpret_cast<const float4*>(hidden + (size_t)row * Hv);
    const float4* wp = reinterpret_cast<const float4*>(W);

    float acc = 0.f;
#pragma unroll
    for (int k = 0; k < 4; ++k) {
        float4 h = hp[lane + k * 64];
        float4 w = wp[lane + k * 64];
        acc += h.x * w.x + h.y * w.y + h.z * w.z + h.w * w.w;
    }

    // 64-lane butterfly reduce
#pragma unroll
    for (int off = 32; off >= 1; off >>= 1)
        acc += __shfl_down(acc, off, 64);

    if (lane == 0) {
        float t = acc + bias[0];
        if (t > 0.f) {
            int id = ids[row];
            if (id >= 4) {
                int b = row >> 10;               // S = 1024
                atomicMax(reinterpret_cast<int*>(out + (size_t)b * Vv + id),
                          __float_as_int(t));
            }
        }
    }
}

extern "C" void kernel_launch(void* const* d_in, const int* in_sizes, int n_in,
                              void* d_out, int out_size, void* d_ws, size_t ws_size,
                              hipStream_t stream) {
    const float* hidden = (const float*)d_in[0];   // [B, S, H] fp32
    const int*   ids    = (const int*)  d_in[1];   // [B, S] int32
    const float* W      = (const float*)d_in[2];   // [1, H] fp32
    const float* bias   = (const float*)d_in[3];   // [1] fp32
    float*       out    = (float*)d_out;           // [B, V] fp32

    // 1) zero the output table every call (graph replays don't re-poison)
    const int n4 = (Bv * Vv) / 4;                  // 2,000,016
    const int zb = 256;
    int zgrid = (n4 + zb - 1) / zb;
    if (zgrid > 2048) zgrid = 2048;                // grid-stride the rest
    zero_out_kernel<<<zgrid, zb, 0, stream>>>(reinterpret_cast<float4*>(out), n4);

    // 2) dot + relu + scatter-max
    const int rows = Bv * Sv;                      // 32768
    dot_scatter_kernel<<<rows / 4, 256, 0, stream>>>(hidden, ids, W, bias, out);
}